// Round 21
// baseline (55.198 us; speedup 1.0000x reference)
//
#include <hip/hip_runtime.h>
#include <hip/hip_bf16.h>

#define NKVH 4
#define SEQ 4096
#define BLK 64
#define NW 8
#define NQB 64

typedef __attribute__((ext_vector_type(8))) short bf16x8;
typedef __attribute__((ext_vector_type(4))) float f32x4;

// round-half-up f32->bf16 pair pack: [bf16(hi)<<16 | bf16(lo)] (validated r1-r20)
__device__ __forceinline__ unsigned pkbf(unsigned lo, unsigned hi) {
  return __builtin_amdgcn_perm(hi + 0x8000u, lo + 0x8000u, 0x07060302u);
}

__device__ __forceinline__ void gload16(const void* g, void* l) {
  __builtin_amdgcn_global_load_lds(
      (const __attribute__((address_space(1))) void*)g,
      (__attribute__((address_space(3))) void*)l, 16, 0, 0);
}

// ---- pre-pass: K (pi_f-permuted rows) and V^T -> bf16, MFMA-fragment-linear.
//      kvh==0 blocks also scan their 64-element seg slice (sorted -> unique
//      first-occurrence writer, plain store, no init). Unchanged from r17. ----
__global__ __launch_bounds__(256, 2)
void prep_kernel(const float* __restrict__ kp, const float* __restrict__ vp,
                 const int* __restrict__ seg,
                 short* __restrict__ kw, short* __restrict__ vt,
                 int* __restrict__ fo)
{
  const int ki = blockIdx.x, kvh = blockIdx.y, b = blockIdx.z;
  const size_t base = (((size_t)(b*NKVH + kvh)*SEQ) + (size_t)ki*BLK)*64;
  __shared__ float sk[64][72];
  __shared__ float sv[64][72];
  const int t = threadIdx.x;
  #pragma unroll
  for (int it = 0; it < 4; ++it) {
    const int i = t + it*256;
    const int row = i >> 4, c4 = i & 15;
    float4 a = *(const float4*)(kp + base + row*64 + c4*4);
    *(float4*)&sk[row][c4*4] = a;
    float4 v = *(const float4*)(vp + base + row*64 + c4*4);
    *(float4*)&sv[row][c4*4] = v;
  }
  if (kvh == 0 && t < BLK) {
    const int idx = ki*BLK + t;
    const int v = seg[b*SEQ + idx];
    const bool bnd = (idx == 0) || (seg[b*SEQ + idx - 1] != v);
    if (bnd) fo[b*8 + v] = idx;
  }
  __syncthreads();
  #pragma unroll
  for (int it = 0; it < 2; ++it) {
    const int o = t + it*256;
    const int s = o >> 8, fd = (o >> 6) & 3, lg = (o >> 4) & 3, lr = o & 15;
    const int krow = 8*(lr >> 2) + (lr & 3) + 4*(fd & 1) + 32*(fd >> 1);
    const float* src = &sk[krow][s*32 + lg*8];
    uint4 w;
    w.x = pkbf(__float_as_uint(src[0]), __float_as_uint(src[1]));
    w.y = pkbf(__float_as_uint(src[2]), __float_as_uint(src[3]));
    w.z = pkbf(__float_as_uint(src[4]), __float_as_uint(src[5]));
    w.w = pkbf(__float_as_uint(src[6]), __float_as_uint(src[7]));
    *(uint4*)(kw + base + (size_t)o*8) = w;
    const int d = fd*16 + lr;
    const int n0 = s*32 + lg*8;
    uint4 u;
    u.x = pkbf(__float_as_uint(sv[n0+0][d]), __float_as_uint(sv[n0+1][d]));
    u.y = pkbf(__float_as_uint(sv[n0+2][d]), __float_as_uint(sv[n0+3][d]));
    u.z = pkbf(__float_as_uint(sv[n0+4][d]), __float_as_uint(sv[n0+5][d]));
    u.w = pkbf(__float_as_uint(sv[n0+6][d]), __float_as_uint(sv[n0+7][d]));
    *(uint4*)(vt + base + (size_t)o*8) = u;
  }
}

// ---- main: split-KV — 512 thr, 8 waves = 2 halves x (2 heads x 2 row-halves).
//      Half h handles windows h*4..h*4+3 with its own LDS double-buffer;
//      additive no-max softmax lets halves combine via LDS at the end. ----
__global__ __launch_bounds__(512, 2)
void sattn_kernel(const float* __restrict__ qp, const short* __restrict__ kw,
                  const short* __restrict__ vt, const float* __restrict__ alibi,
                  const int* __restrict__ seg, const int* __restrict__ bidx,
                  const int* __restrict__ fo, float* __restrict__ outp)
{
  const int raw = blockIdx.x;              // 1024 blocks = 8 XCDs x 128
  const int xcd = raw & 7, li = raw >> 3;
  const int b = xcd >> 2, kvh = xcd & 3;
  const int qb = li & 63, hp = li >> 6;

  const int tid = threadIdx.x;
  const int wave = tid >> 6, lane = tid & 63;
  const int lr = lane & 15, lg = lane >> 4;
  const int half = wave >> 2, sub = wave & 3;
  const int hh = sub & 1, wq = sub >> 1;
  const int head = kvh*4 + hp*2 + hh;
  const int tloc = tid & 255, wloc = (tid >> 6) & 3;

  __shared__ short klds[2][2][4096];   // [half][buf]
  __shared__ short vlds[2][2][4096];

  int kis[4];
  #pragma unroll
  for (int i = 0; i < 4; ++i) kis[i] = bidx[qb*NW + half*4 + i];

  int m_glob[2], lo[2];
  unsigned relm[2];
  #pragma unroll
  for (int g = 0; g < 2; ++g) {
    m_glob[g] = qb*BLK + (wq*2 + g)*16 + lr;
    const int sv = seg[b*SEQ + m_glob[g]];
    lo[g] = fo[b*8 + sv];
    relm[g] = (unsigned)(m_glob[g] - lo[g]);
  }
  const float LOG2E = 1.4426950408889634f;
  const float nslope = -alibi[head] * LOG2E;

  // hoisted ALiBi constants: score = qk + A[g] - B(kt) - cnr[f][r]
  float A2[2], cnr[4][4];
  #pragma unroll
  for (int g = 0; g < 2; ++g) A2[g] = nslope * (float)m_glob[g];
  #pragma unroll
  for (int f = 0; f < 4; ++f) {
    const int nb = lg*8 + 4*(f & 1) + 32*(f >> 1);
    #pragma unroll
    for (int r = 0; r < 4; ++r) cnr[f][r] = nslope * (float)(nb + r);
  }

  const short* kbase = kw + ((size_t)(b*NKVH + kvh)*SEQ)*64;
  const short* vbase = vt + ((size_t)(b*NKVH + kvh)*SEQ)*64;

  auto STAGE = [&](int buf, int j) {
    const int ki = kis[j] < 0 ? 0 : kis[j];
    const char* ksrc = (const char*)(kbase + (size_t)ki*4096);
    const char* vsrc = (const char*)(vbase + (size_t)ki*4096);
    char* kdst = (char*)&klds[half][buf][0];
    char* vdst = (char*)&vlds[half][buf][0];
    gload16(ksrc + tloc*16,        kdst + wloc*1024);
    gload16(ksrc + 4096 + tloc*16, kdst + 4096 + wloc*1024);
    gload16(vsrc + tloc*16,        vdst + wloc*1024);
    gload16(vsrc + 4096 + tloc*16, vdst + 4096 + wloc*1024);
  };

  STAGE(0, 0);

  // Q (scaled by 0.125*log2e) into registers, bf16, for both row-groups
  bf16x8 qf[2][2];   // [g][s]
  {
    const float qs = 0.125f * LOG2E;
    #pragma unroll
    for (int g = 0; g < 2; ++g) {
      const float* qrow = qp + (((size_t)b*16 + head)*SEQ + m_glob[g])*64;
      #pragma unroll
      for (int s = 0; s < 2; ++s) {
        float4 a = *(const float4*)(qrow + s*32 + lg*8);
        float4 c = *(const float4*)(qrow + s*32 + lg*8 + 4);
        union { unsigned u[4]; bf16x8 v; } cv;
        cv.u[0] = pkbf(__float_as_uint(a.x*qs), __float_as_uint(a.y*qs));
        cv.u[1] = pkbf(__float_as_uint(a.z*qs), __float_as_uint(a.w*qs));
        cv.u[2] = pkbf(__float_as_uint(c.x*qs), __float_as_uint(c.y*qs));
        cv.u[3] = pkbf(__float_as_uint(c.z*qs), __float_as_uint(c.w*qs));
        qf[g][s] = cv.v;
      }
    }
  }

  // all-ones A-fragment for row-sum MFMA
  union { unsigned short us[8]; bf16x8 v; } one_u;
  #pragma unroll
  for (int i = 0; i < 8; ++i) one_u.us[i] = 0x3F80;
  const bf16x8 onesf = one_u.v;

  f32x4 oacc[2][4], osum[2];
  #pragma unroll
  for (int g = 0; g < 2; ++g) {
    f32x4 z = {0.f,0.f,0.f,0.f};
    osum[g] = z;
    #pragma unroll
    for (int dt = 0; dt < 4; ++dt) oacc[g][dt] = z;
  }

  asm volatile("s_waitcnt vmcnt(0)" ::: "memory");
  __builtin_amdgcn_s_barrier();

  #pragma unroll
  for (int j = 0; j < 4; ++j) {
    if (j < 3) STAGE((j + 1) & 1, j + 1);   // issued right after barrier
    const int kvi = kis[j];
    if (kvi >= 0) {
      const int wiG = half*4 + j;
      const float B = nslope * (float)(kvi*BLK);
      const bool fast = (wiG != NW-1) &&
          __all((kvi*BLK >= lo[0]) && (kvi*BLK >= lo[1]));

      // ---- QK^T with ALiBi bias folded into the accumulator init ----
      f32x4 sacc[2][4];
      #pragma unroll
      for (int g = 0; g < 2; ++g) {
        const float Dg = A2[g] - B;
        #pragma unroll
        for (int f = 0; f < 4; ++f)
          #pragma unroll
          for (int r = 0; r < 4; ++r) sacc[g][f][r] = Dg - cnr[f][r];
      }
      #pragma unroll
      for (int s = 0; s < 2; ++s) {
        bf16x8 kf[4];
        #pragma unroll
        for (int f = 0; f < 4; ++f)
          kf[f] = *(const bf16x8*)&klds[half][j & 1][(s*256 + f*64 + lane)*8];
        __builtin_amdgcn_s_setprio(1);
        #pragma unroll
        for (int f = 0; f < 4; ++f)
          sacc[0][f] = __builtin_amdgcn_mfma_f32_16x16x32_bf16(kf[f], qf[0][s], sacc[0][f], 0, 0, 0);
        #pragma unroll
        for (int f = 0; f < 4; ++f)
          sacc[1][f] = __builtin_amdgcn_mfma_f32_16x16x32_bf16(kf[f], qf[1][s], sacc[1][f], 0, 0, 0);
        __builtin_amdgcn_s_setprio(0);
      }

      // ---- exp + pack (fast: no mask; slow: interval cndmask incl. causal) ----
      union { unsigned u[4]; bf16x8 v; } pfs[2][2];
      if (fast) {
        #pragma unroll
        for (int g = 0; g < 2; ++g)
          #pragma unroll
          for (int f = 0; f < 4; ++f) {
            const float p0 = __builtin_amdgcn_exp2f(sacc[g][f][0]);
            const float p1 = __builtin_amdgcn_exp2f(sacc[g][f][1]);
            const float p2 = __builtin_amdgcn_exp2f(sacc[g][f][2]);
            const float p3 = __builtin_amdgcn_exp2f(sacc[g][f][3]);
            pfs[g][f >> 1].u[(f & 1)*2 + 0] = pkbf(__float_as_uint(p0), __float_as_uint(p1));
            pfs[g][f >> 1].u[(f & 1)*2 + 1] = pkbf(__float_as_uint(p2), __float_as_uint(p3));
          }
      } else {
        #pragma unroll
        for (int g = 0; g < 2; ++g)
          #pragma unroll
          for (int f = 0; f < 4; ++f) {
            const int nb = lg*8 + 4*(f & 1) + 32*(f >> 1);
            const unsigned nrel0 = (unsigned)(kvi*BLK + nb - lo[g]);
            float p[4];
            #pragma unroll
            for (int r = 0; r < 4; ++r) {
              const bool live = (nrel0 + (unsigned)r) <= relm[g];
              const float pv = __builtin_amdgcn_exp2f(sacc[g][f][r]);
              p[r] = live ? pv : 0.f;
            }
            pfs[g][f >> 1].u[(f & 1)*2 + 0] = pkbf(__float_as_uint(p[0]), __float_as_uint(p[1]));
            pfs[g][f >> 1].u[(f & 1)*2 + 1] = pkbf(__float_as_uint(p[2]), __float_as_uint(p[3]));
          }
      }

      // ---- PV + ones-MFMA row sums ----
      #pragma unroll
      for (int s = 0; s < 2; ++s) {
        bf16x8 vf[4];
        #pragma unroll
        for (int dt = 0; dt < 4; ++dt)
          vf[dt] = *(const bf16x8*)&vlds[half][j & 1][(s*256 + dt*64 + lane)*8];
        __builtin_amdgcn_s_setprio(1);
        #pragma unroll
        for (int dt = 0; dt < 4; ++dt)
          oacc[0][dt] = __builtin_amdgcn_mfma_f32_16x16x32_bf16(vf[dt], pfs[0][s].v, oacc[0][dt], 0, 0, 0);
        #pragma unroll
        for (int dt = 0; dt < 4; ++dt)
          oacc[1][dt] = __builtin_amdgcn_mfma_f32_16x16x32_bf16(vf[dt], pfs[1][s].v, oacc[1][dt], 0, 0, 0);
        osum[0] = __builtin_amdgcn_mfma_f32_16x16x32_bf16(onesf, pfs[0][s].v, osum[0], 0, 0, 0);
        osum[1] = __builtin_amdgcn_mfma_f32_16x16x32_bf16(onesf, pfs[1][s].v, osum[1], 0, 0, 0);
        __builtin_amdgcn_s_setprio(0);
      }
    }
    if (j < 3) {
      asm volatile("s_waitcnt vmcnt(0)" ::: "memory");
      __builtin_amdgcn_s_barrier();
    }
  }

  // ---- combine halves: no-max softmax partials are additive ----
  __syncthreads();   // all compute done; LDS free for reuse
  float* cl_o = (float*)&klds[0][0][0];   // 32 KB: 256 slots x 32 floats
  float* cl_s = (float*)&vlds[0][0][0];
  const int slot = sub*64 + lane;
  if (half == 1) {
    #pragma unroll
    for (int g = 0; g < 2; ++g)
      #pragma unroll
      for (int dt = 0; dt < 4; ++dt)
        #pragma unroll
        for (int r = 0; r < 4; ++r)
          cl_o[slot*32 + ((g*16 + dt*4 + r + lane) & 31)] = oacc[g][dt][r];
    cl_s[slot*2 + 0] = osum[0][0];
    cl_s[slot*2 + 1] = osum[1][0];
  }
  __syncthreads();
  if (half == 0) {
    #pragma unroll
    for (int g = 0; g < 2; ++g)
      #pragma unroll
      for (int dt = 0; dt < 4; ++dt)
        #pragma unroll
        for (int r = 0; r < 4; ++r)
          oacc[g][dt][r] += cl_o[slot*32 + ((g*16 + dt*4 + r + lane) & 31)];
    const float l0 = osum[0][0] + cl_s[slot*2 + 0];
    const float l1 = osum[1][0] + cl_s[slot*2 + 1];
    const float lr2[2] = {l0, l1};
    #pragma unroll
    for (int g = 0; g < 2; ++g) {
      const float inv = lr2[g] > 0.f ? 1.f/lr2[g] : 0.f;
      float* dst = outp + (((size_t)b*16 + head)*SEQ + m_glob[g])*64;
      #pragma unroll
      for (int dt = 0; dt < 4; ++dt) {
        float4 o;
        o.x = oacc[g][dt][0]*inv; o.y = oacc[g][dt][1]*inv;
        o.z = oacc[g][dt][2]*inv; o.w = oacc[g][dt][3]*inv;
        *(float4*)&dst[dt*16 + lg*4] = o;
      }
    }
  }
}

extern "C" void kernel_launch(void* const* d_in, const int* in_sizes, int n_in,
                              void* d_out, int out_size, void* d_ws, size_t ws_size,
                              hipStream_t stream) {
  const float* q    = (const float*)d_in[0];
  const float* k    = (const float*)d_in[1];
  const float* v    = (const float*)d_in[2];
  const float* al   = (const float*)d_in[3];
  const int*   sg   = (const int*)d_in[4];
  const int*   bi   = (const int*)d_in[5];
  short* kws  = (short*)d_ws;                              // 4 MiB
  short* vtws = (short*)((char*)d_ws + (size_t)(1u<<22));  // 4 MiB
  int*   fo   = (int*)((char*)d_ws + (size_t)(1u<<23));    // 64 B
  dim3 pgrid(NQB, NKVH, 2);
  prep_kernel<<<pgrid, 256, 0, stream>>>(k, v, sg, kws, vtws, fo);
  sattn_kernel<<<dim3(1024), 512, 0, stream>>>(q, kws, vtws, al, sg, bi, fo, (float*)d_out);
}

// Round 22
// 44.244 us; speedup vs baseline: 1.2476x; 1.2476x over previous
//
#include <hip/hip_runtime.h>
#include <hip/hip_bf16.h>

#define NKVH 4
#define SEQ 4096
#define BLK 64
#define NW 8
#define NQB 64

typedef __attribute__((ext_vector_type(8))) short bf16x8;
typedef __attribute__((ext_vector_type(4))) float f32x4;

// round-half-up f32->bf16 pair pack: [bf16(hi)<<16 | bf16(lo)] (validated r1-r19)
__device__ __forceinline__ unsigned pkbf(unsigned lo, unsigned hi) {
  return __builtin_amdgcn_perm(hi + 0x8000u, lo + 0x8000u, 0x07060302u);
}

__device__ __forceinline__ void gload16(const void* g, void* l) {
  __builtin_amdgcn_global_load_lds(
      (const __attribute__((address_space(1))) void*)g,
      (__attribute__((address_space(3))) void*)l, 16, 0, 0);
}

// ---- pre-pass: K (pi_f-permuted rows) and V^T -> bf16, MFMA-fragment-linear.
//      kvh==0 blocks also scan their 64-element seg slice (sorted -> unique
//      first-occurrence writer, plain store, no init). ----
__global__ __launch_bounds__(256, 2)
void prep_kernel(const float* __restrict__ kp, const float* __restrict__ vp,
                 const int* __restrict__ seg,
                 short* __restrict__ kw, short* __restrict__ vt,
                 int* __restrict__ fo)
{
  const int ki = blockIdx.x, kvh = blockIdx.y, b = blockIdx.z;
  const size_t base = (((size_t)(b*NKVH + kvh)*SEQ) + (size_t)ki*BLK)*64;
  __shared__ float sk[64][72];
  __shared__ float sv[64][72];
  const int t = threadIdx.x;
  #pragma unroll
  for (int it = 0; it < 4; ++it) {
    const int i = t + it*256;
    const int row = i >> 4, c4 = i & 15;
    float4 a = *(const float4*)(kp + base + row*64 + c4*4);
    *(float4*)&sk[row][c4*4] = a;
    float4 v = *(const float4*)(vp + base + row*64 + c4*4);
    *(float4*)&sv[row][c4*4] = v;
  }
  if (kvh == 0 && t < BLK) {
    const int idx = ki*BLK + t;
    const int v = seg[b*SEQ + idx];
    const bool bnd = (idx == 0) || (seg[b*SEQ + idx - 1] != v);
    if (bnd) fo[b*8 + v] = idx;
  }
  __syncthreads();
  #pragma unroll
  for (int it = 0; it < 2; ++it) {
    const int o = t + it*256;
    const int s = o >> 8, fd = (o >> 6) & 3, lg = (o >> 4) & 3, lr = o & 15;
    const int krow = 8*(lr >> 2) + (lr & 3) + 4*(fd & 1) + 32*(fd >> 1);
    const float* src = &sk[krow][s*32 + lg*8];
    uint4 w;
    w.x = pkbf(__float_as_uint(src[0]), __float_as_uint(src[1]));
    w.y = pkbf(__float_as_uint(src[2]), __float_as_uint(src[3]));
    w.z = pkbf(__float_as_uint(src[4]), __float_as_uint(src[5]));
    w.w = pkbf(__float_as_uint(src[6]), __float_as_uint(src[7]));
    *(uint4*)(kw + base + (size_t)o*8) = w;
    const int d = fd*16 + lr;
    const int n0 = s*32 + lg*8;
    uint4 u;
    u.x = pkbf(__float_as_uint(sv[n0+0][d]), __float_as_uint(sv[n0+1][d]));
    u.y = pkbf(__float_as_uint(sv[n0+2][d]), __float_as_uint(sv[n0+3][d]));
    u.z = pkbf(__float_as_uint(sv[n0+4][d]), __float_as_uint(sv[n0+5][d]));
    u.w = pkbf(__float_as_uint(sv[n0+6][d]), __float_as_uint(sv[n0+7][d]));
    *(uint4*)(vt + base + (size_t)o*8) = u;
  }
}

// ---- main: 3-buffer staging + counted vmcnt(4) (T4), ALiBi-in-accumulator,
//      fast-path mask, P-in-regs, ones-MFMA row sums ----
__global__ __launch_bounds__(256, 2)
void sattn_kernel(const float* __restrict__ qp, const short* __restrict__ kw,
                  const short* __restrict__ vt, const float* __restrict__ alibi,
                  const int* __restrict__ seg, const int* __restrict__ bidx,
                  const int* __restrict__ fo, float* __restrict__ outp)
{
  const int raw = blockIdx.x;
  const int xcd = raw & 7, li = raw >> 3;
  const int b = xcd >> 2, kvh = xcd & 3;
  const int qb = li & 63, hp = li >> 6;

  const int tid = threadIdx.x;
  const int wave = tid >> 6, lane = tid & 63;
  const int lr = lane & 15, lg = lane >> 4;
  const int wh = wave & 1, wq = wave >> 1;   // head-in-pair, row-half
  const int head = kvh*4 + hp*2 + wh;

  __shared__ short klds[3][4096];   // 3 buffers: compute wi, landed wi+1, in-flight wi+2
  __shared__ short vlds[3][4096];

  int kis[NW];
  #pragma unroll
  for (int i = 0; i < NW; ++i) kis[i] = bidx[qb*NW + i];

  int m_glob[2], lo[2];
  unsigned relm[2];
  #pragma unroll
  for (int g = 0; g < 2; ++g) {
    m_glob[g] = qb*BLK + (wq*2 + g)*16 + lr;
    const int sv = seg[b*SEQ + m_glob[g]];
    lo[g] = fo[b*8 + sv];
    relm[g] = (unsigned)(m_glob[g] - lo[g]);
  }
  const float LOG2E = 1.4426950408889634f;
  const float nslope = -alibi[head] * LOG2E;

  // hoisted ALiBi constants: score = qk + A[g] - B(wi) - cnr[f][r]
  float A2[2], cnr[4][4];
  #pragma unroll
  for (int g = 0; g < 2; ++g) A2[g] = nslope * (float)m_glob[g];
  #pragma unroll
  for (int f = 0; f < 4; ++f) {
    const int nb = lg*8 + 4*(f & 1) + 32*(f >> 1);
    #pragma unroll
    for (int r = 0; r < 4; ++r) cnr[f][r] = nslope * (float)(nb + r);
  }

  const short* kbase = kw + ((size_t)(b*NKVH + kvh)*SEQ)*64;
  const short* vbase = vt + ((size_t)(b*NKVH + kvh)*SEQ)*64;

  auto STAGE = [&](int buf, int wi) {
    const int ki = kis[wi] < 0 ? 0 : kis[wi];
    const char* ksrc = (const char*)(kbase + (size_t)ki*4096);
    const char* vsrc = (const char*)(vbase + (size_t)ki*4096);
    gload16(ksrc + tid*16,        (char*)&klds[buf][0] + wave*1024);
    gload16(ksrc + 4096 + tid*16, (char*)&klds[buf][0] + 4096 + wave*1024);
    gload16(vsrc + tid*16,        (char*)&vlds[buf][0] + wave*1024);
    gload16(vsrc + 4096 + tid*16, (char*)&vlds[buf][0] + 4096 + wave*1024);
  };

  STAGE(0, 0);
  STAGE(1, 1);

  // Q (scaled by 0.125*log2e) into registers, bf16, for both row-groups
  bf16x8 qf[2][2];   // [g][s]
  {
    const float qs = 0.125f * LOG2E;
    #pragma unroll
    for (int g = 0; g < 2; ++g) {
      const float* qrow = qp + (((size_t)b*16 + head)*SEQ + m_glob[g])*64;
      #pragma unroll
      for (int s = 0; s < 2; ++s) {
        float4 a = *(const float4*)(qrow + s*32 + lg*8);
        float4 c = *(const float4*)(qrow + s*32 + lg*8 + 4);
        union { unsigned u[4]; bf16x8 v; } cv;
        cv.u[0] = pkbf(__float_as_uint(a.x*qs), __float_as_uint(a.y*qs));
        cv.u[1] = pkbf(__float_as_uint(a.z*qs), __float_as_uint(a.w*qs));
        cv.u[2] = pkbf(__float_as_uint(c.x*qs), __float_as_uint(c.y*qs));
        cv.u[3] = pkbf(__float_as_uint(c.z*qs), __float_as_uint(c.w*qs));
        qf[g][s] = cv.v;
      }
    }
  }

  // all-ones A-fragment for row-sum MFMA
  union { unsigned short us[8]; bf16x8 v; } one_u;
  #pragma unroll
  for (int i = 0; i < 8; ++i) one_u.us[i] = 0x3F80;
  const bf16x8 onesf = one_u.v;

  f32x4 oacc[2][4], osum[2];
  #pragma unroll
  for (int g = 0; g < 2; ++g) {
    f32x4 z = {0.f,0.f,0.f,0.f};
    osum[g] = z;
    #pragma unroll
    for (int dt = 0; dt < 4; ++dt) oacc[g][dt] = z;
  }

  // prologue: drain everything (Q + STAGE(0),STAGE(1)); then sync
  asm volatile("s_waitcnt vmcnt(0)" ::: "memory");
  __builtin_amdgcn_s_barrier();

  #pragma unroll
  for (int wi = 0; wi < NW; ++wi) {
    // issue STAGE(wi+2) immediately after barrier — overwrites buf (wi-1)%3,
    // whose readers all passed the previous barrier
    if (wi + 2 < NW) STAGE((wi + 2) % 3, wi + 2);

    const int kvi = kis[wi];
    if (kvi >= 0) {
      const float B = nslope * (float)(kvi*BLK);
      const bool fast = (wi != NW-1) &&
          __all((kvi*BLK >= lo[0]) && (kvi*BLK >= lo[1]));

      // ---- QK^T with ALiBi bias folded into the accumulator init ----
      f32x4 sacc[2][4];
      #pragma unroll
      for (int g = 0; g < 2; ++g) {
        const float Dg = A2[g] - B;
        #pragma unroll
        for (int f = 0; f < 4; ++f)
          #pragma unroll
          for (int r = 0; r < 4; ++r) sacc[g][f][r] = Dg - cnr[f][r];
      }
      #pragma unroll
      for (int s = 0; s < 2; ++s) {
        bf16x8 kf[4];
        #pragma unroll
        for (int f = 0; f < 4; ++f)
          kf[f] = *(const bf16x8*)&klds[wi % 3][(s*256 + f*64 + lane)*8];
        __builtin_amdgcn_s_setprio(1);
        #pragma unroll
        for (int f = 0; f < 4; ++f)
          sacc[0][f] = __builtin_amdgcn_mfma_f32_16x16x32_bf16(kf[f], qf[0][s], sacc[0][f], 0, 0, 0);
        #pragma unroll
        for (int f = 0; f < 4; ++f)
          sacc[1][f] = __builtin_amdgcn_mfma_f32_16x16x32_bf16(kf[f], qf[1][s], sacc[1][f], 0, 0, 0);
        __builtin_amdgcn_s_setprio(0);
      }

      // ---- exp + pack (fast: no mask; slow: interval cndmask) ----
      union { unsigned u[4]; bf16x8 v; } pfs[2][2];
      if (fast) {
        #pragma unroll
        for (int g = 0; g < 2; ++g)
          #pragma unroll
          for (int f = 0; f < 4; ++f) {
            const float p0 = __builtin_amdgcn_exp2f(sacc[g][f][0]);
            const float p1 = __builtin_amdgcn_exp2f(sacc[g][f][1]);
            const float p2 = __builtin_amdgcn_exp2f(sacc[g][f][2]);
            const float p3 = __builtin_amdgcn_exp2f(sacc[g][f][3]);
            pfs[g][f >> 1].u[(f & 1)*2 + 0] = pkbf(__float_as_uint(p0), __float_as_uint(p1));
            pfs[g][f >> 1].u[(f & 1)*2 + 1] = pkbf(__float_as_uint(p2), __float_as_uint(p3));
          }
      } else {
        #pragma unroll
        for (int g = 0; g < 2; ++g)
          #pragma unroll
          for (int f = 0; f < 4; ++f) {
            const int nb = lg*8 + 4*(f & 1) + 32*(f >> 1);
            const unsigned nrel0 = (unsigned)(kvi*BLK + nb - lo[g]);
            float p[4];
            #pragma unroll
            for (int r = 0; r < 4; ++r) {
              const bool live = (nrel0 + (unsigned)r) <= relm[g];
              const float pv = __builtin_amdgcn_exp2f(sacc[g][f][r]);
              p[r] = live ? pv : 0.f;
            }
            pfs[g][f >> 1].u[(f & 1)*2 + 0] = pkbf(__float_as_uint(p[0]), __float_as_uint(p[1]));
            pfs[g][f >> 1].u[(f & 1)*2 + 1] = pkbf(__float_as_uint(p[2]), __float_as_uint(p[3]));
          }
      }

      // ---- PV + ones-MFMA row sums ----
      #pragma unroll
      for (int s = 0; s < 2; ++s) {
        bf16x8 vf[4];
        #pragma unroll
        for (int dt = 0; dt < 4; ++dt)
          vf[dt] = *(const bf16x8*)&vlds[wi % 3][(s*256 + dt*64 + lane)*8];
        __builtin_amdgcn_s_setprio(1);
        #pragma unroll
        for (int dt = 0; dt < 4; ++dt)
          oacc[0][dt] = __builtin_amdgcn_mfma_f32_16x16x32_bf16(vf[dt], pfs[0][s].v, oacc[0][dt], 0, 0, 0);
        #pragma unroll
        for (int dt = 0; dt < 4; ++dt)
          oacc[1][dt] = __builtin_amdgcn_mfma_f32_16x16x32_bf16(vf[dt], pfs[1][s].v, oacc[1][dt], 0, 0, 0);
        osum[0] = __builtin_amdgcn_mfma_f32_16x16x32_bf16(onesf, pfs[0][s].v, osum[0], 0, 0, 0);
        osum[1] = __builtin_amdgcn_mfma_f32_16x16x32_bf16(onesf, pfs[1][s].v, osum[1], 0, 0, 0);
        __builtin_amdgcn_s_setprio(0);
      }
    }

    if (wi + 1 < NW) {
      // counted wait: STAGE(wi+1) must have landed; STAGE(wi+2)'s 4 loads may fly
      if (wi + 2 < NW) asm volatile("s_waitcnt vmcnt(4)" ::: "memory");
      else             asm volatile("s_waitcnt vmcnt(0)" ::: "memory");
      __builtin_amdgcn_s_barrier();
    }
  }

  // ---- epilogue: osum[g][0] is the full row sum ----
  #pragma unroll
  for (int g = 0; g < 2; ++g) {
    const float lrow = osum[g][0];
    const float inv = lrow > 0.f ? 1.f/lrow : 0.f;
    float* dst = outp + (((size_t)b*16 + head)*SEQ + m_glob[g])*64;
    #pragma unroll
    for (int dt = 0; dt < 4; ++dt) {
      float4 o;
      o.x = oacc[g][dt][0]*inv; o.y = oacc[g][dt][1]*inv;
      o.z = oacc[g][dt][2]*inv; o.w = oacc[g][dt][3]*inv;
      *(float4*)&dst[dt*16 + lg*4] = o;
    }
  }
}

extern "C" void kernel_launch(void* const* d_in, const int* in_sizes, int n_in,
                              void* d_out, int out_size, void* d_ws, size_t ws_size,
                              hipStream_t stream) {
  const float* q    = (const float*)d_in[0];
  const float* k    = (const float*)d_in[1];
  const float* v    = (const float*)d_in[2];
  const float* al   = (const float*)d_in[3];
  const int*   sg   = (const int*)d_in[4];
  const int*   bi   = (const int*)d_in[5];
  short* kws  = (short*)d_ws;                              // 4 MiB
  short* vtws = (short*)((char*)d_ws + (size_t)(1u<<22));  // 4 MiB
  int*   fo   = (int*)((char*)d_ws + (size_t)(1u<<23));    // 64 B
  dim3 pgrid(NQB, NKVH, 2);
  prep_kernel<<<pgrid, 256, 0, stream>>>(k, v, sg, kws, vtws, fo);
  sattn_kernel<<<dim3(1024), 256, 0, stream>>>(q, kws, vtws, al, sg, bi, fo, (float*)d_out);
}